// Round 1
// baseline (138.100 us; speedup 1.0000x reference)
//
#include <hip/hip_runtime.h>

// DigitConvolutionalModel: conv3x3(valid) + 3-layer MLP, fused.
// Round 1: fp32 baseline.
//   Kernel A: Weff[784][100] = conv kernel folded into W1 (linear in x).
//   Kernel B: per 128-row block: GEMM1 (K=784, LDS-tiled) -> relu
//             -> GEMM2 (K=100, LDS) -> relu -> GEMM3 -> out.

#define BM 128
#define BK 56
#define NT 320   // 32 row-threads x 10 col-threads; per-thread tile 4x10

__global__ void build_weff(const float* __restrict__ w_conv,
                           const float* __restrict__ W1,
                           float* __restrict__ weff) {
    const int j = threadIdx.x;          // output feature 0..99
    const int p = blockIdx.x;           // pixel 0..783
    if (j >= 100) return;
    const int y  = p / 28;
    const int xx = p % 28;
    float s = 0.f;
#pragma unroll
    for (int ky = 0; ky < 3; ++ky) {
        const int py = y - ky;
        if (py < 0 || py >= 26) continue;
#pragma unroll
        for (int kx = 0; kx < 3; ++kx) {
            const int px = xx - kx;
            if (px < 0 || px >= 26) continue;
            s += w_conv[ky * 3 + kx] * W1[(py * 26 + px) * 100 + j];
        }
    }
    weff[p * 100 + j] = s;
}

union SMem {
    struct { float xs[BK][132];  float ws[BK][104]; } p1;                  // 52,864 B
    struct { float ht[100][132]; float w2[100][104]; float w3[1000]; } p2; // 98,400 B
};

__global__ __launch_bounds__(NT)
void fused_mlp(const float* __restrict__ x,
               const float* __restrict__ weff,
               const float* __restrict__ b1,
               const float* __restrict__ W2,
               const float* __restrict__ b2,
               const float* __restrict__ W3,
               const float* __restrict__ b3,
               float* __restrict__ out) {
    __shared__ SMem sm;
    const int tid = threadIdx.x;
    const int rt  = tid / 10;   // 0..31  -> rows rt*4 .. rt*4+3
    const int ct  = tid % 10;   // 0..9   -> cols ct*10 .. ct*10+9
    const int b0  = blockIdx.x * BM;

    float acc[4][10];
#pragma unroll
    for (int i = 0; i < 4; ++i)
#pragma unroll
        for (int j = 0; j < 10; ++j) acc[i][j] = 0.f;

    // ---------------- Phase 1: h1_pre = x @ Weff  (K = 784, 14 tiles of 56)
    for (int kt = 0; kt < 784 / BK; ++kt) {
        // stage x tile, transposed: xs[k][m]
#pragma unroll
        for (int it = 0; it < 6; ++it) {
            const int f = tid + NT * it;
            if (f < BM * (BK / 4)) {                 // 1792 float4 loads
                const int m  = f / (BK / 4);
                const int k4 = f % (BK / 4);
                const float4 v = *reinterpret_cast<const float4*>(
                    x + (size_t)(b0 + m) * 784 + kt * BK + k4 * 4);
                sm.p1.xs[k4 * 4 + 0][m] = v.x;
                sm.p1.xs[k4 * 4 + 1][m] = v.y;
                sm.p1.xs[k4 * 4 + 2][m] = v.z;
                sm.p1.xs[k4 * 4 + 3][m] = v.w;
            }
        }
        // stage Weff tile: ws[k][j]
#pragma unroll
        for (int it = 0; it < 5; ++it) {
            const int f = tid + NT * it;
            if (f < BK * 25) {                        // 1400 float4 loads
                const int k  = f / 25;
                const int j4 = f % 25;
                const float4 v = *reinterpret_cast<const float4*>(
                    weff + (size_t)(kt * BK + k) * 100 + j4 * 4);
                *reinterpret_cast<float4*>(&sm.p1.ws[k][j4 * 4]) = v;
            }
        }
        __syncthreads();

#pragma unroll 2
        for (int k = 0; k < BK; ++k) {
            const float4 a4 = *reinterpret_cast<const float4*>(&sm.p1.xs[k][rt * 4]);
            const float av[4] = {a4.x, a4.y, a4.z, a4.w};
            float bv[10];
#pragma unroll
            for (int u = 0; u < 5; ++u) {
                const float2 t = *reinterpret_cast<const float2*>(&sm.p1.ws[k][ct * 10 + 2 * u]);
                bv[2 * u] = t.x; bv[2 * u + 1] = t.y;
            }
#pragma unroll
            for (int i = 0; i < 4; ++i)
#pragma unroll
                for (int j = 0; j < 10; ++j)
                    acc[i][j] = fmaf(av[i], bv[j], acc[i][j]);
        }
        __syncthreads();
    }

    // ---------------- h1 = relu(acc + b1), store transposed ht[j][m]
    float bias[10];
#pragma unroll
    for (int j = 0; j < 10; ++j) bias[j] = b1[ct * 10 + j];
#pragma unroll
    for (int i = 0; i < 4; ++i)
#pragma unroll
        for (int j = 0; j < 10; ++j) {
            float v = acc[i][j] + bias[j];
            sm.p2.ht[ct * 10 + j][rt * 4 + i] = v > 0.f ? v : 0.f;
        }
    // stage W2 -> w2[k][j]
#pragma unroll
    for (int it = 0; it < 8; ++it) {
        const int f = tid + NT * it;
        if (f < 2500) {
            const int k  = f / 25;
            const int j4 = f % 25;
            const float4 v = *reinterpret_cast<const float4*>(W2 + (size_t)k * 100 + j4 * 4);
            *reinterpret_cast<float4*>(&sm.p2.w2[k][j4 * 4]) = v;
        }
    }
    // stage W3 (100x10)
#pragma unroll
    for (int it = 0; it < 4; ++it) {
        const int f = tid + NT * it;
        if (f < 1000) sm.p2.w3[f] = W3[f];
    }
    __syncthreads();

    // ---------------- Phase 2: h2 = relu(h1 @ W2 + b2)
    float acc2[4][10];
#pragma unroll
    for (int i = 0; i < 4; ++i)
#pragma unroll
        for (int j = 0; j < 10; ++j) acc2[i][j] = 0.f;

#pragma unroll 2
    for (int k = 0; k < 100; ++k) {
        const float4 a4 = *reinterpret_cast<const float4*>(&sm.p2.ht[k][rt * 4]);
        const float av[4] = {a4.x, a4.y, a4.z, a4.w};
        float bv[10];
#pragma unroll
        for (int u = 0; u < 5; ++u) {
            const float2 t = *reinterpret_cast<const float2*>(&sm.p2.w2[k][ct * 10 + 2 * u]);
            bv[2 * u] = t.x; bv[2 * u + 1] = t.y;
        }
#pragma unroll
        for (int i = 0; i < 4; ++i)
#pragma unroll
            for (int j = 0; j < 10; ++j)
                acc2[i][j] = fmaf(av[i], bv[j], acc2[i][j]);
    }
    __syncthreads();   // all reads of ht done before overwrite

#pragma unroll
    for (int j = 0; j < 10; ++j) bias[j] = b2[ct * 10 + j];
#pragma unroll
    for (int i = 0; i < 4; ++i)
#pragma unroll
        for (int j = 0; j < 10; ++j) {
            float v = acc2[i][j] + bias[j];
            sm.p2.ht[ct * 10 + j][rt * 4 + i] = v > 0.f ? v : 0.f;  // now holds h2^T
        }
    __syncthreads();

    // ---------------- Phase 3: out = h2 @ W3 + b3   (128x10 per block)
#pragma unroll
    for (int q = 0; q < 4; ++q) {
        const int o   = tid + NT * q;    // < 1280 always
        const int row = o / 10;
        const int c   = o % 10;
        float s = b3[c];
#pragma unroll 4
        for (int j = 0; j < 100; ++j)
            s = fmaf(sm.p2.ht[j][row], sm.p2.w3[j * 10 + c], s);
        out[(size_t)(b0 + row) * 10 + c] = s;
    }
}

extern "C" void kernel_launch(void* const* d_in, const int* in_sizes, int n_in,
                              void* d_out, int out_size, void* d_ws, size_t ws_size,
                              hipStream_t stream) {
    const float* x      = (const float*)d_in[0];
    const float* w_conv = (const float*)d_in[1];
    const float* W1     = (const float*)d_in[2];
    const float* b1     = (const float*)d_in[3];
    const float* W2     = (const float*)d_in[4];
    const float* b2     = (const float*)d_in[5];
    const float* W3     = (const float*)d_in[6];
    const float* b3     = (const float*)d_in[7];
    float* out  = (float*)d_out;
    float* weff = (float*)d_ws;   // 78,400 floats = 313.6 KB scratch

    build_weff<<<784, 128, 0, stream>>>(w_conv, W1, weff);
    fused_mlp<<<32768 / BM, NT, 0, stream>>>(x, weff, b1, W2, b2, W3, b3, out);
}

// Round 2
// 44.556 us; speedup vs baseline: 3.0995x; 3.0995x over previous
//
#include <hip/hip_runtime.h>

// R2: conv folded into Weff (bf16, transposed, padded) + fully-MFMA fused MLP.
// GEMM1: [32768x832]x[832x112] bf16 MFMA 16x16x32, K-staged through LDS.
// GEMM2: [128x128]x[128x112]   (K=100 padded to 128, pads zeroed)
// GEMM3: [128x128]x[128x16]    (W3 in cols 0..9)
// Single bf16 (no hi/lo split): predicted absmax ~0.02 << 0.075 threshold.

typedef __attribute__((ext_vector_type(8))) short     bf16x8;
typedef __attribute__((ext_vector_type(4))) float     f32x4;
typedef __attribute__((ext_vector_type(8))) unsigned short u16x8;

__device__ __forceinline__ unsigned short f2bf(float f) {
    unsigned int u = __float_as_uint(f);
    u += 0x7FFFu + ((u >> 16) & 1u);          // RNE
    return (unsigned short)(u >> 16);
}

#define KP1 832     // K of GEMM1, padded (784 -> 13*64)
#define NP  112     // N padded (100 -> 7*16)
#define BM  128
#define NT  256     // 4 waves

// ---- Kernel A: Weff^T[j][p] = sum_kxy w_conv[ky][kx] * W1[(y-ky)*26+(x-kx)][j]
__global__ void build_weff_t(const float* __restrict__ w_conv,
                             const float* __restrict__ W1,
                             unsigned short* __restrict__ weff_t) {
    const int idx = blockIdx.x * 256 + threadIdx.x;
    if (idx >= NP * KP1) return;
    const int j = idx / KP1;        // feature col 0..111
    const int p = idx % KP1;        // pixel (K) 0..831
    float s = 0.f;
    if (j < 100 && p < 784) {
        const int y = p / 28, xx = p % 28;
#pragma unroll
        for (int ky = 0; ky < 3; ++ky) {
            const int py = y - ky;
            if (py < 0 || py >= 26) continue;
#pragma unroll
            for (int kx = 0; kx < 3; ++kx) {
                const int px = xx - kx;
                if (px < 0 || px >= 26) continue;
                s += w_conv[ky * 3 + kx] * W1[(py * 26 + px) * 100 + j];
            }
        }
    }
    weff_t[(size_t)j * KP1 + p] = f2bf(s);
}

// LDS: strides 72/136 ushorts -> 16B-aligned b128, worst 2-way bank aliasing.
union SMem {
    struct { unsigned short a[BM][72];  unsigned short b[NP][72];  } g1; // 34,560 B
    struct { unsigned short a[BM][136]; unsigned short w[NP][136]; } g2; // 65,280 B
};

__global__ __launch_bounds__(NT)
void fused_mfma(const float* __restrict__ x,
                const unsigned short* __restrict__ weff_t,
                const float* __restrict__ b1,
                const float* __restrict__ W2,
                const float* __restrict__ b2,
                const float* __restrict__ W3,
                const float* __restrict__ b3,
                float* __restrict__ out) {
    __shared__ SMem sm;
    const int tid  = threadIdx.x;
    const int lane = tid & 63;
    const int wv   = tid >> 6;        // 0..3
    const int mrow = wv * 32;         // wave's 32 rows
    const int l15  = lane & 15;
    const int lk   = lane >> 4;       // 0..3
    const int b0   = blockIdx.x * BM;

    f32x4 acc[2][7];
#pragma unroll
    for (int m = 0; m < 2; ++m)
#pragma unroll
        for (int n = 0; n < 7; ++n) acc[m][n] = (f32x4){0.f, 0.f, 0.f, 0.f};

    // staging registers (T14: issue loads early, write after barrier)
    float4 xa[8];
    u16x8  wb[4];

    auto load_stage = [&](int kt) {
        const int k0 = kt * 64;
#pragma unroll
        for (int q = 0; q < 8; ++q) {               // x tile: 128x64 fp32
            const int f   = q * NT + tid;
            const int row = f >> 4;
            const int c4  = f & 15;
            if (k0 + c4 * 4 < 784)
                xa[q] = *reinterpret_cast<const float4*>(
                    x + (size_t)(b0 + row) * 784 + k0 + c4 * 4);
            else
                xa[q] = (float4){0.f, 0.f, 0.f, 0.f};
        }
#pragma unroll
        for (int q = 0; q < 4; ++q) {               // Weff^T tile: 112x64 bf16
            const int f = q * NT + tid;
            if (f < NP * 8) {
                const int col = f >> 3, c8 = f & 7;
                wb[q] = *reinterpret_cast<const u16x8*>(
                    weff_t + (size_t)col * KP1 + k0 + c8 * 8);
            }
        }
    };
    auto write_stage = [&]() {
#pragma unroll
        for (int q = 0; q < 8; ++q) {
            const int f = q * NT + tid;
            const int row = f >> 4, c4 = f & 15;
            unsigned short p0 = f2bf(xa[q].x), p1 = f2bf(xa[q].y);
            unsigned short p2 = f2bf(xa[q].z), p3 = f2bf(xa[q].w);
            unsigned int w0 = (unsigned int)p0 | ((unsigned int)p1 << 16);
            unsigned int w1 = (unsigned int)p2 | ((unsigned int)p3 << 16);
            *reinterpret_cast<uint2*>(&sm.g1.a[row][c4 * 4]) = (uint2){w0, w1};
        }
#pragma unroll
        for (int q = 0; q < 4; ++q) {
            const int f = q * NT + tid;
            if (f < NP * 8) {
                const int col = f >> 3, c8 = f & 7;
                *reinterpret_cast<u16x8*>(&sm.g1.b[col][c8 * 8]) = wb[q];
            }
        }
    };

    // ---------------- GEMM1: 13 stages of BK=64
    load_stage(0);
    for (int kt = 0; kt < 13; ++kt) {
        __syncthreads();                 // previous compute done reading LDS
        write_stage();
        __syncthreads();
        if (kt < 12) load_stage(kt + 1); // in flight during compute
#pragma unroll
        for (int ks = 0; ks < 2; ++ks) {
            const int kb = ks * 32 + lk * 8;
            bf16x8 af[2];
#pragma unroll
            for (int m = 0; m < 2; ++m)
                af[m] = *reinterpret_cast<const bf16x8*>(&sm.g1.a[mrow + m * 16 + l15][kb]);
#pragma unroll
            for (int n = 0; n < 7; ++n) {
                const bf16x8 bf_ = *reinterpret_cast<const bf16x8*>(&sm.g1.b[n * 16 + l15][kb]);
#pragma unroll
                for (int m = 0; m < 2; ++m)
                    acc[m][n] = __builtin_amdgcn_mfma_f32_16x16x32_bf16(af[m], bf_, acc[m][n], 0, 0, 0);
            }
        }
    }

    // bias for this lane's 7 cols
    float bias1[7], bias2[7];
#pragma unroll
    for (int n = 0; n < 7; ++n) {
        const int c = n * 16 + l15;
        bias1[n] = (c < 100) ? b1[c] : 0.f;
        bias2[n] = (c < 100) ? b2[c] : 0.f;
    }

    __syncthreads();    // all GEMM1 LDS reads done before union overwrite

    // ---------------- h1 = relu(acc + b1) -> g2.a (bf16), K-pad zeroed
#pragma unroll
    for (int m = 0; m < 2; ++m)
#pragma unroll
        for (int n = 0; n < 7; ++n) {
            const int col = n * 16 + l15;
            if (col < 100) {
#pragma unroll
                for (int q = 0; q < 4; ++q) {
                    float v = acc[m][n][q] + bias1[n];
                    v = fmaxf(v, 0.f);
                    sm.g2.a[mrow + m * 16 + lk * 4 + q][col] = f2bf(v);
                }
            }
        }
    for (int f = tid; f < BM * 36; f += NT) {          // zero k = 100..135
        sm.g2.a[f / 36][100 + f % 36] = 0;
    }
    for (int f = tid; f < NP * 36; f += NT) {          // zero W2^T k-pad (0xNaN hazard)
        sm.g2.w[f / 36][100 + f % 36] = 0;
    }
    for (int f = tid; f < 10000; f += NT) {            // W2^T[col][k] = W2[k][col]
        const int k = f / 100, col = f % 100;
        sm.g2.w[col][k] = f2bf(W2[f]);
    }
    __syncthreads();

    // ---------------- GEMM2: K=128 (4 k-steps)
    f32x4 acc2[2][7];
#pragma unroll
    for (int m = 0; m < 2; ++m)
#pragma unroll
        for (int n = 0; n < 7; ++n) acc2[m][n] = (f32x4){0.f, 0.f, 0.f, 0.f};
#pragma unroll
    for (int ks = 0; ks < 4; ++ks) {
        const int kb = ks * 32 + lk * 8;
        bf16x8 af[2];
#pragma unroll
        for (int m = 0; m < 2; ++m)
            af[m] = *reinterpret_cast<const bf16x8*>(&sm.g2.a[mrow + m * 16 + l15][kb]);
#pragma unroll
        for (int n = 0; n < 7; ++n) {
            const bf16x8 bf_ = *reinterpret_cast<const bf16x8*>(&sm.g2.w[n * 16 + l15][kb]);
#pragma unroll
            for (int m = 0; m < 2; ++m)
                acc2[m][n] = __builtin_amdgcn_mfma_f32_16x16x32_bf16(af[m], bf_, acc2[m][n], 0, 0, 0);
        }
    }
    __syncthreads();    // all GEMM2 reads done before overwriting g2.a / g2.w

    // ---------------- h2 = relu(acc2 + b2) -> g2.a ; stage W3 into g2.w[0..15]
#pragma unroll
    for (int m = 0; m < 2; ++m)
#pragma unroll
        for (int n = 0; n < 7; ++n) {
            const int col = n * 16 + l15;
            if (col < 100) {
#pragma unroll
                for (int q = 0; q < 4; ++q) {
                    float v = acc2[m][n][q] + bias2[n];
                    v = fmaxf(v, 0.f);
                    sm.g2.a[mrow + m * 16 + lk * 4 + q][col] = f2bf(v);
                }
            }
        }
    for (int f = tid; f < 16 * 36; f += NT) {          // zero W3^T k-pad
        sm.g2.w[f / 36][100 + f % 36] = 0;
    }
    for (int f = tid; f < 1000; f += NT) {             // W3^T[col][k] = W3[k][col]
        const int k = f / 10, col = f % 10;
        sm.g2.w[col][k] = f2bf(W3[f]);
    }
    __syncthreads();

    // ---------------- GEMM3: out = h2 @ W3 + b3
    f32x4 acc3[2];
#pragma unroll
    for (int m = 0; m < 2; ++m) acc3[m] = (f32x4){0.f, 0.f, 0.f, 0.f};
#pragma unroll
    for (int ks = 0; ks < 4; ++ks) {
        const int kb = ks * 32 + lk * 8;
        const bf16x8 bf_ = *reinterpret_cast<const bf16x8*>(&sm.g2.w[l15][kb]);
#pragma unroll
        for (int m = 0; m < 2; ++m) {
            const bf16x8 af = *reinterpret_cast<const bf16x8*>(&sm.g2.a[mrow + m * 16 + l15][kb]);
            acc3[m] = __builtin_amdgcn_mfma_f32_16x16x32_bf16(af, bf_, acc3[m], 0, 0, 0);
        }
    }

    if (l15 < 10) {
        const float bb = b3[l15];
#pragma unroll
        for (int m = 0; m < 2; ++m)
#pragma unroll
            for (int q = 0; q < 4; ++q) {
                const int row = b0 + mrow + m * 16 + lk * 4 + q;
                out[(size_t)row * 10 + l15] = acc3[m][q] + bb;
            }
    }
}

extern "C" void kernel_launch(void* const* d_in, const int* in_sizes, int n_in,
                              void* d_out, int out_size, void* d_ws, size_t ws_size,
                              hipStream_t stream) {
    const float* x      = (const float*)d_in[0];
    const float* w_conv = (const float*)d_in[1];
    const float* W1     = (const float*)d_in[2];
    const float* b1     = (const float*)d_in[3];
    const float* W2     = (const float*)d_in[4];
    const float* b2     = (const float*)d_in[5];
    const float* W3     = (const float*)d_in[6];
    const float* b3     = (const float*)d_in[7];
    float* out = (float*)d_out;
    unsigned short* weff_t = (unsigned short*)d_ws;   // 112*832*2 = 186,368 B

    build_weff_t<<<(NP * KP1 + 255) / 256, 256, 0, stream>>>(w_conv, W1, weff_t);
    fused_mfma<<<32768 / BM, NT, 0, stream>>>(x, weff_t, b1, W2, b2, W3, b3, out);
}